// Round 1
// baseline (1047.845 us; speedup 1.0000x reference)
//
#include <hip/hip_runtime.h>
#include <math.h>

#define NN 32
#define MM 64
#define BATCH 512
#define ITERS 1000

// workspace layout (floats)
#define OFF_S    0
#define OFF_SD   16                    // 64x64 = s*D, row-major
#define OFF_PHT  (16 + 4096)           // 32x64 = P^-1 H^T
#define OFF_HINV (16 + 4096 + 2048)    // 32x64 = pinv(H)

__device__ __forceinline__ void gauss_jordan32(float (&GJ)[32][64], int lane) {
  // In-place Gauss-Jordan on [A | I] (32x64), 64 lanes = columns. SPD input, no pivoting.
  #pragma unroll 1
  for (int k = 0; k < 32; ++k) {
    float inv = 1.0f / GJ[k][k];
    float rk = GJ[k][lane] * inv;
    GJ[k][lane] = rk;
    __syncthreads();
    #pragma unroll 1
    for (int i = 0; i < 32; ++i) {
      if (i == k) continue;
      float f = GJ[i][k];               // broadcast read (pre-update, program order)
      GJ[i][lane] = fmaf(-f, rk, GJ[i][lane]);
    }
    __syncthreads();
  }
}

__global__ void setup_kernel(const float* __restrict__ P,
                             const float* __restrict__ H,
                             float* __restrict__ ws) {
  __shared__ __align__(16) float GJ[32][64];
  __shared__ __align__(16) float Hl[64][36];   // pad 36: 144B rows, 16B-aligned, bank-safe
  __shared__ __align__(16) float vl[64];
  const int lane = threadIdx.x;

  // load H row `lane` into regs + LDS (both blocks need it)
  float hreg[32];
  {
    const float4* hp = (const float4*)(H + lane * 32);
    #pragma unroll
    for (int j4 = 0; j4 < 8; ++j4) {
      float4 t = hp[j4];
      hreg[4*j4+0] = t.x; hreg[4*j4+1] = t.y; hreg[4*j4+2] = t.z; hreg[4*j4+3] = t.w;
      Hl[lane][4*j4+0] = t.x; Hl[lane][4*j4+1] = t.y; Hl[lane][4*j4+2] = t.z; Hl[lane][4*j4+3] = t.w;
    }
  }
  __syncthreads();

  if (blockIdx.x == 0) {
    // ---------------- block A: Pinv, PinvHt, D, lambda_max, sD ----------------
    for (int idx = lane; idx < 1024; idx += 64) {
      int r = idx >> 5, c = idx & 31;
      GJ[r][c] = P[idx];
      GJ[r][32 + c] = (r == c) ? 1.0f : 0.0f;
    }
    __syncthreads();
    gauss_jordan32(GJ, lane);

    // PinvHt[r][lane] = sum_j Pinv[r][j] * H[lane][j]   (lane = column of PinvHt)
    float pht[32];
    #pragma unroll 1
    for (int r = 0; r < 32; ++r) {
      float a0 = 0.f, a1 = 0.f, a2 = 0.f, a3 = 0.f;
      #pragma unroll
      for (int j4 = 0; j4 < 8; ++j4) {
        float4 pv = *(const float4*)&GJ[r][32 + 4*j4];   // broadcast
        a0 = fmaf(pv.x, hreg[4*j4+0], a0);
        a1 = fmaf(pv.y, hreg[4*j4+1], a1);
        a2 = fmaf(pv.z, hreg[4*j4+2], a2);
        a3 = fmaf(pv.w, hreg[4*j4+3], a3);
      }
      float val = (a0 + a1) + (a2 + a3);
      pht[r] = val;
      ws[OFF_PHT + r*64 + lane] = val;
    }

    // D column `lane` (D symmetric): dcol[r] = D[r][lane] = sum_j H[r][j]*pht[j]
    float dcol[64];
    #pragma unroll 1
    for (int r = 0; r < 64; ++r) {
      float a0 = 0.f, a1 = 0.f, a2 = 0.f, a3 = 0.f;
      #pragma unroll
      for (int j4 = 0; j4 < 8; ++j4) {
        float4 hv = *(const float4*)&Hl[r][4*j4];        // broadcast
        a0 = fmaf(hv.x, pht[4*j4+0], a0);
        a1 = fmaf(hv.y, pht[4*j4+1], a1);
        a2 = fmaf(hv.z, pht[4*j4+2], a2);
        a3 = fmaf(hv.w, pht[4*j4+3], a3);
      }
      dcol[r] = (a0 + a1) + (a2 + a3);
    }

    // power iteration for lambda_max(D); D column held in regs, v broadcast via LDS
    float v = 1.0f + 0.017f * (float)lane;
    #pragma unroll 1
    for (int t = 0; t < 320; ++t) {
      vl[lane] = v;
      __syncthreads();
      float a0 = 0.f, a1 = 0.f, a2 = 0.f, a3 = 0.f;
      #pragma unroll
      for (int j4 = 0; j4 < 16; ++j4) {
        float4 vv = *(const float4*)&vl[4*j4];           // broadcast
        a0 = fmaf(dcol[4*j4+0], vv.x, a0);
        a1 = fmaf(dcol[4*j4+1], vv.y, a1);
        a2 = fmaf(dcol[4*j4+2], vv.z, a2);
        a3 = fmaf(dcol[4*j4+3], vv.w, a3);
      }
      v = (a0 + a1) + (a2 + a3);
      if ((t & 7) == 7) {
        float n2 = v * v;
        #pragma unroll
        for (int m = 1; m < 64; m <<= 1) n2 += __shfl_xor(n2, m);
        v *= 1.0f / sqrtf(n2);
      }
      __syncthreads();
    }
    // Rayleigh quotient
    vl[lane] = v;
    __syncthreads();
    {
      float a0 = 0.f, a1 = 0.f, a2 = 0.f, a3 = 0.f;
      #pragma unroll
      for (int j4 = 0; j4 < 16; ++j4) {
        float4 vv = *(const float4*)&vl[4*j4];
        a0 = fmaf(dcol[4*j4+0], vv.x, a0);
        a1 = fmaf(dcol[4*j4+1], vv.y, a1);
        a2 = fmaf(dcol[4*j4+2], vv.z, a2);
        a3 = fmaf(dcol[4*j4+3], vv.w, a3);
      }
      float w = (a0 + a1) + (a2 + a3);
      float num = w * v, den = v * v;
      #pragma unroll
      for (int m = 1; m < 64; m <<= 1) {
        num += __shfl_xor(num, m);
        den += __shfl_xor(den, m);
      }
      float s = den / num;              // s = BETA / lambda_max, BETA = 1
      if (lane == 0) ws[OFF_S] = s;
      #pragma unroll 1
      for (int r = 0; r < 64; ++r) ws[OFF_SD + r*64 + lane] = s * dcol[r];
    }
  } else {
    // ---------------- block B: Hinv = (H^T H)^-1 H^T ----------------
    int c = lane & 31, hh = lane >> 5;
    #pragma unroll 1
    for (int r = hh * 16; r < hh * 16 + 16; ++r) {
      float acc = 0.f;
      #pragma unroll 4
      for (int j = 0; j < 64; ++j) acc = fmaf(Hl[j][r], Hl[j][c], acc);
      GJ[r][c] = acc;
      GJ[r][32 + c] = (r == c) ? 1.0f : 0.0f;
    }
    __syncthreads();
    gauss_jordan32(GJ, lane);
    // Hinv[r][lane] = sum_j Ginv[r][j] * H[lane][j]
    #pragma unroll 1
    for (int r = 0; r < 32; ++r) {
      float a0 = 0.f, a1 = 0.f, a2 = 0.f, a3 = 0.f;
      #pragma unroll
      for (int j4 = 0; j4 < 8; ++j4) {
        float4 gv = *(const float4*)&GJ[r][32 + 4*j4];
        a0 = fmaf(gv.x, hreg[4*j4+0], a0);
        a1 = fmaf(gv.y, hreg[4*j4+1], a1);
        a2 = fmaf(gv.z, hreg[4*j4+2], a2);
        a3 = fmaf(gv.w, hreg[4*j4+3], a3);
      }
      ws[OFF_HINV + r*64 + lane] = (a0 + a1) + (a2 + a3);
    }
  }
}

// one wave per batch row; lane i holds row i of sD in 64 VGPRs
__global__ __launch_bounds__(64) void iter_kernel(const float* __restrict__ q,
                                                  const float* __restrict__ bmat,
                                                  const float* __restrict__ ws,
                                                  float* __restrict__ Xs) {
  const int row = blockIdx.x, lane = threadIdx.x;
  __shared__ __align__(16) float x1buf[64];

  float sdr[64];
  {
    const float4* sp = (const float4*)(ws + OFF_SD + lane * 64);
    #pragma unroll
    for (int j4 = 0; j4 < 16; ++j4) {
      float4 t = sp[j4];
      sdr[4*j4+0] = t.x; sdr[4*j4+1] = t.y; sdr[4*j4+2] = t.z; sdr[4*j4+3] = t.w;
    }
  }
  const float s = ws[OFF_S];
  float acc = 0.f;
  {
    const float* qrow = q + row * 32;   // row-uniform -> scalar loads
    #pragma unroll
    for (int j = 0; j < 32; ++j) acc = fmaf(qrow[j], ws[OFF_PHT + j*64 + lane], acc);
  }
  const float mu = s * (acc - bmat[row * 64 + lane]);

  float x1 = 0.f, x2 = 0.f;
  float* Xp = Xs + (size_t)row * (ITERS + 1) * 128;
  Xp[lane] = 0.f;                       // X0 = 0
  Xp[64 + lane] = 0.f;

  #pragma unroll 1
  for (int k = 1; k <= ITERS; ++k) {
    x1buf[lane] = x1;
    __syncthreads();
    float a0 = 0.f, a1 = 0.f, a2 = 0.f, a3 = 0.f;
    #pragma unroll
    for (int j4 = 0; j4 < 16; ++j4) {
      float4 vv = *(const float4*)&x1buf[4*j4];   // same-address broadcast read
      a0 = fmaf(sdr[4*j4+0], vv.x, a0);
      a1 = fmaf(sdr[4*j4+1], vv.y, a1);
      a2 = fmaf(sdr[4*j4+2], vv.z, a2);
      a3 = fmaf(sdr[4*j4+3], vv.w, a3);
    }
    float x1n = (a0 + a1) + (a2 + a3) + fmaf(s, x2, mu);
    float x2n = fmaxf(x1 + x2 - 2.0f * x1n, 0.f);
    Xp += 128;
    Xp[lane] = x1n;
    Xp[64 + lane] = x2n;
    x1 = x1n; x2 = x2n;
    __syncthreads();
  }
}

// primal_sols[b][k][i] = sum_j Hinv[i][j] * (Xs[b][k][64+j] - b[b][j])
__global__ __launch_bounds__(256) void primal_kernel(const float* __restrict__ bmat,
                                                     const float* __restrict__ ws,
                                                     const float* __restrict__ Xs,
                                                     float* __restrict__ out2) {
  const int row = blockIdx.x;
  const int lane = threadIdx.x & 63, wv = threadIdx.x >> 6;
  const int i = lane & 31, h = lane >> 5;
  __shared__ __align__(16) float tbuf[4][64];

  float hv[32];   // half-row of Hinv: h=0 -> j 0..31, h=1 -> j 32..63
  {
    const float4* hp = (const float4*)(ws + OFF_HINV + i * 64 + h * 32);
    #pragma unroll
    for (int j4 = 0; j4 < 8; ++j4) {
      float4 t = hp[j4];
      hv[4*j4+0] = t.x; hv[4*j4+1] = t.y; hv[4*j4+2] = t.z; hv[4*j4+3] = t.w;
    }
  }
  const float bl = bmat[row * 64 + lane];
  const float* Xb = Xs + (size_t)row * (ITERS + 1) * 128 + 64;
  float* ob = out2 + (size_t)row * (ITERS + 1) * 32;

  for (int k = wv; k <= ITERS; k += 4) {     // per-wave independent; no block barrier
    float t = Xb[(size_t)k * 128 + lane] - bl;
    tbuf[wv][lane] = t;
    __builtin_amdgcn_wave_barrier();          // compiler fence; DS pipe is in-order per wave
    float a0 = 0.f, a1 = 0.f, a2 = 0.f, a3 = 0.f;
    const float4* tp = (const float4*)&tbuf[wv][h * 32];
    #pragma unroll
    for (int j4 = 0; j4 < 8; ++j4) {
      float4 vv = tp[j4];
      a0 = fmaf(hv[4*j4+0], vv.x, a0);
      a1 = fmaf(hv[4*j4+1], vv.y, a1);
      a2 = fmaf(hv[4*j4+2], vv.z, a2);
      a3 = fmaf(hv[4*j4+3], vv.w, a3);
    }
    float p = (a0 + a1) + (a2 + a3);
    p += __shfl_xor(p, 32);                   // combine j-halves
    if (h == 0) ob[(size_t)k * 32 + i] = p;
    __builtin_amdgcn_wave_barrier();          // keep next tbuf write after these reads
  }
}

extern "C" void kernel_launch(void* const* d_in, const int* in_sizes, int n_in,
                              void* d_out, int out_size, void* d_ws, size_t ws_size,
                              hipStream_t stream) {
  (void)in_sizes; (void)n_in; (void)out_size; (void)ws_size;
  const float* q = (const float*)d_in[0];
  const float* b = (const float*)d_in[1];
  const float* P = (const float*)d_in[2];
  const float* H = (const float*)d_in[3];
  float* ws = (float*)d_ws;
  float* Xs = (float*)d_out;
  float* out2 = Xs + (size_t)BATCH * (ITERS + 1) * 128;

  setup_kernel<<<2, 64, 0, stream>>>(P, H, ws);
  iter_kernel<<<BATCH, 64, 0, stream>>>(q, b, ws, Xs);
  primal_kernel<<<BATCH, 256, 0, stream>>>(b, ws, Xs, out2);
}

// Round 2
// 685.122 us; speedup vs baseline: 1.5294x; 1.5294x over previous
//
#include <hip/hip_runtime.h>
#include <math.h>

#define BATCH 512
#define ITERS 1000

// workspace layout (floats)
#define OFF_S    0
#define OFF_SD   16                    // 64x64 = s*D, row-major
#define OFF_PHT  (16 + 4096)           // 32x64 = P^-1 H^T
#define OFF_HINV (16 + 4096 + 2048)    // 32x64 = pinv(H)

__device__ __forceinline__ float rdlane(float v, int l) {
  return __int_as_float(__builtin_amdgcn_readlane(__float_as_int(v), l));
}

// Register-resident Gauss-Jordan on [A|I] (32x64); lane holds column `lane`
// of each augmented row r in g[r]. Broadcasts via v_readlane (uniform SGPR).
#define GJ32_REG(g)                                            \
  _Pragma("unroll")                                            \
  for (int k = 0; k < 32; ++k) {                               \
    float inv = 1.0f / rdlane(g[k], k);                        \
    g[k] *= inv;                                               \
    _Pragma("unroll")                                          \
    for (int i = 0; i < 32; ++i) {                             \
      if (i == k) continue;                                    \
      float f = rdlane(g[i], k);                               \
      g[i] = fmaf(-f, g[k], g[i]);                             \
    }                                                          \
  }

__global__ __launch_bounds__(64) void setup_kernel(const float* __restrict__ P,
                                                   const float* __restrict__ H,
                                                   float* __restrict__ ws) {
  __shared__ float Hl[64][36];
  const int lane = threadIdx.x;

  float hreg[32];                       // H[lane][0..31]
  {
    const float4* hp = (const float4*)(H + lane * 32);
    #pragma unroll
    for (int j4 = 0; j4 < 8; ++j4) {
      float4 t = hp[j4];
      hreg[4*j4+0] = t.x; hreg[4*j4+1] = t.y; hreg[4*j4+2] = t.z; hreg[4*j4+3] = t.w;
    }
  }

  if (blockIdx.x == 0) {
    // ---------------- block A: Pinv, PinvHt, D, lambda_max, sD ----------------
    float g[32];
    #pragma unroll
    for (int r = 0; r < 32; ++r) {
      float pv = P[r*32 + (lane & 31)];
      g[r] = (lane < 32) ? pv : (((lane - 32) == r) ? 1.0f : 0.0f);
    }
    GJ32_REG(g)

    // pht[r] = (P^-1 H^T)[r][lane] = sum_j Pinv[r][j] * H[lane][j]
    float pht[32];
    #pragma unroll
    for (int r = 0; r < 32; ++r) {
      float a0 = 0.f, a1 = 0.f;
      #pragma unroll
      for (int j = 0; j < 32; j += 2) {
        a0 = fmaf(rdlane(g[r], 32 + j),     hreg[j],     a0);
        a1 = fmaf(rdlane(g[r], 32 + j + 1), hreg[j + 1], a1);
      }
      pht[r] = a0 + a1;
      ws[OFF_PHT + r*64 + lane] = pht[r];
    }

    // dcol[r] = D[r][lane] = sum_j H[r][j] * pht[j]   (D symmetric)
    float dcol[64];
    #pragma unroll
    for (int r = 0; r < 64; ++r) {
      float a0 = 0.f, a1 = 0.f;
      #pragma unroll
      for (int j = 0; j < 32; j += 2) {
        a0 = fmaf(rdlane(hreg[j],     r), pht[j],     a0);
        a1 = fmaf(rdlane(hreg[j + 1], r), pht[j + 1], a1);
      }
      dcol[r] = a0 + a1;
    }

    // E = D^2 (symmetric): ecol[r] = E[r][lane] = sum_c D[r][c] * D[c][lane]
    // Power-iterating E doubles convergence per matvec.
    float ecol[64];
    #pragma unroll
    for (int r = 0; r < 64; ++r) {
      float a0 = 0.f, a1 = 0.f;
      #pragma unroll
      for (int c = 0; c < 64; c += 2) {
        a0 = fmaf(rdlane(dcol[r], c),     dcol[c],     a0);
        a1 = fmaf(rdlane(dcol[r], c + 1), dcol[c + 1], a1);
      }
      ecol[r] = a0 + a1;
    }

    // power iteration on E (equiv. 224 D-steps; Rayleigh on D squares residual)
    float v = 1.0f + 0.017f * (float)lane;
    #pragma unroll 1
    for (int t = 0; t < 112; ++t) {
      float a0 = 0.f, a1 = 0.f, a2 = 0.f, a3 = 0.f;
      #pragma unroll
      for (int c = 0; c < 64; c += 4) {
        a0 = fmaf(ecol[c+0], rdlane(v, c+0), a0);
        a1 = fmaf(ecol[c+1], rdlane(v, c+1), a1);
        a2 = fmaf(ecol[c+2], rdlane(v, c+2), a2);
        a3 = fmaf(ecol[c+3], rdlane(v, c+3), a3);
      }
      v = (a0 + a1) + (a2 + a3);
      if ((t & 7) == 7) {
        float n2 = v * v;
        #pragma unroll
        for (int m = 1; m < 64; m <<= 1) n2 += __shfl_xor(n2, m);
        v *= 1.0f / sqrtf(n2);
      }
    }
    // Rayleigh quotient with D
    {
      float a0 = 0.f, a1 = 0.f, a2 = 0.f, a3 = 0.f;
      #pragma unroll
      for (int c = 0; c < 64; c += 4) {
        a0 = fmaf(dcol[c+0], rdlane(v, c+0), a0);
        a1 = fmaf(dcol[c+1], rdlane(v, c+1), a1);
        a2 = fmaf(dcol[c+2], rdlane(v, c+2), a2);
        a3 = fmaf(dcol[c+3], rdlane(v, c+3), a3);
      }
      float w = (a0 + a1) + (a2 + a3);
      float num = w * v, den = v * v;
      #pragma unroll
      for (int m = 1; m < 64; m <<= 1) {
        num += __shfl_xor(num, m);
        den += __shfl_xor(den, m);
      }
      float s = den / num;              // s = BETA / lambda_max, BETA = 1
      if (lane == 0) ws[OFF_S] = s;
      #pragma unroll
      for (int r = 0; r < 64; ++r) ws[OFF_SD + r*64 + lane] = s * dcol[r];
    }
  } else {
    // ---------------- block B: Hinv = (H^T H)^-1 H^T ----------------
    #pragma unroll
    for (int j = 0; j < 32; ++j) Hl[lane][j] = hreg[j];
    __syncthreads();
    float htc[64];                      // htc[m] = H[m][lane&31]
    #pragma unroll
    for (int m = 0; m < 64; ++m) htc[m] = Hl[m][lane & 31];

    float gB[32];
    #pragma unroll
    for (int r = 0; r < 32; ++r) {
      float a0 = 0.f, a1 = 0.f;
      #pragma unroll
      for (int m = 0; m < 64; m += 2) {
        a0 = fmaf(rdlane(hreg[r], m),     htc[m],     a0);
        a1 = fmaf(rdlane(hreg[r], m + 1), htc[m + 1], a1);
      }
      float hth = a0 + a1;              // (H^T H)[r][lane&31]
      gB[r] = (lane < 32) ? hth : (((lane - 32) == r) ? 1.0f : 0.0f);
    }
    GJ32_REG(gB)
    // Hinv[r][lane] = sum_j Ginv[r][j] * H[lane][j]
    #pragma unroll
    for (int r = 0; r < 32; ++r) {
      float a0 = 0.f, a1 = 0.f;
      #pragma unroll
      for (int j = 0; j < 32; j += 2) {
        a0 = fmaf(rdlane(gB[r], 32 + j),     hreg[j],     a0);
        a1 = fmaf(rdlane(gB[r], 32 + j + 1), hreg[j + 1], a1);
      }
      ws[OFF_HINV + r*64 + lane] = a0 + a1;
    }
  }
}

// one wave per batch row; lane i holds row i of sD; x1 broadcast via v_readlane
__global__ __launch_bounds__(64) void iter_kernel(const float* __restrict__ q,
                                                  const float* __restrict__ bmat,
                                                  const float* __restrict__ ws,
                                                  float* __restrict__ Xs) {
  const int row = blockIdx.x, lane = threadIdx.x;

  float sdr[64];
  {
    const float4* sp = (const float4*)(ws + OFF_SD + lane * 64);
    #pragma unroll
    for (int j4 = 0; j4 < 16; ++j4) {
      float4 t = sp[j4];
      sdr[4*j4+0] = t.x; sdr[4*j4+1] = t.y; sdr[4*j4+2] = t.z; sdr[4*j4+3] = t.w;
    }
  }
  const float s = ws[OFF_S];
  float acc = 0.f;
  {
    const float* qrow = q + row * 32;   // row-uniform -> scalar loads
    #pragma unroll
    for (int j = 0; j < 32; ++j) acc = fmaf(qrow[j], ws[OFF_PHT + j*64 + lane], acc);
  }
  const float mu = s * (acc - bmat[row * 64 + lane]);

  float x1 = 0.f, x2 = 0.f;
  float* Xp = Xs + (size_t)row * (ITERS + 1) * 128;
  Xp[lane] = 0.f;                       // X0 = 0
  Xp[64 + lane] = 0.f;

  #pragma unroll 1
  for (int k = 1; k <= ITERS; ++k) {
    float a0 = 0.f, a1 = 0.f, a2 = 0.f, a3 = 0.f;
    #pragma unroll
    for (int j = 0; j < 64; j += 4) {
      a0 = fmaf(sdr[j+0], rdlane(x1, j+0), a0);
      a1 = fmaf(sdr[j+1], rdlane(x1, j+1), a1);
      a2 = fmaf(sdr[j+2], rdlane(x1, j+2), a2);
      a3 = fmaf(sdr[j+3], rdlane(x1, j+3), a3);
    }
    float x1n = ((a0 + a1) + (a2 + a3)) + fmaf(s, x2, mu);
    float x2n = fmaxf(x1 + x2 - 2.0f * x1n, 0.f);
    Xp += 128;
    Xp[lane] = x1n;
    Xp[64 + lane] = x2n;
    x1 = x1n; x2 = x2n;
  }
}

// primal_sols[b][k][i] = sum_j Hinv[i][j] * (Xs[b][k][64+j] - b[b][j])
// 8 waves/block, depth-2 prefetch; LDS half-select for the j-half per lane.
__global__ __launch_bounds__(512) void primal_kernel(const float* __restrict__ bmat,
                                                     const float* __restrict__ ws,
                                                     const float* __restrict__ Xs,
                                                     float* __restrict__ out2) {
  const int row = blockIdx.x;
  const int tid = threadIdx.x;
  const int wv = tid >> 6, lane = tid & 63;
  const int i = lane & 31, h = lane >> 5;
  __shared__ __align__(16) float tbuf[8][64];

  float hv[32];   // half-row of Hinv: h=0 -> j 0..31, h=1 -> j 32..63
  {
    const float4* hp = (const float4*)(ws + OFF_HINV + i * 64 + h * 32);
    #pragma unroll
    for (int j4 = 0; j4 < 8; ++j4) {
      float4 t = hp[j4];
      hv[4*j4+0] = t.x; hv[4*j4+1] = t.y; hv[4*j4+2] = t.z; hv[4*j4+3] = t.w;
    }
  }
  const float bl = bmat[row * 64 + lane];
  const float* Xb = Xs + (size_t)row * (ITERS + 1) * 128 + 64;
  float* ob = out2 + (size_t)row * (ITERS + 1) * 32;

  float tA = Xb[(size_t)wv * 128 + lane] - bl;                          // k = wv
  float tB = (wv + 8 <= ITERS) ? Xb[(size_t)(wv + 8) * 128 + lane] - bl : 0.f;

  #pragma unroll 1
  for (int k = wv; k <= ITERS; k += 8) {
    const int kn = k + 16;
    float tC = (kn <= ITERS) ? Xb[(size_t)kn * 128 + lane] - bl : 0.f;  // prefetch
    tbuf[wv][lane] = tA;
    __builtin_amdgcn_wave_barrier();          // scheduling fence (DS in-order per wave)
    float a0 = 0.f, a1 = 0.f, a2 = 0.f, a3 = 0.f;
    const float4* tp = (const float4*)&tbuf[wv][h * 32];
    #pragma unroll
    for (int j4 = 0; j4 < 8; ++j4) {
      float4 t = tp[j4];
      a0 = fmaf(hv[4*j4+0], t.x, a0);
      a1 = fmaf(hv[4*j4+1], t.y, a1);
      a2 = fmaf(hv[4*j4+2], t.z, a2);
      a3 = fmaf(hv[4*j4+3], t.w, a3);
    }
    float p = (a0 + a1) + (a2 + a3);
    p += __shfl_xor(p, 32);                   // combine j-halves
    if (h == 0) ob[(size_t)k * 32 + i] = p;
    __builtin_amdgcn_wave_barrier();          // next write stays after these reads
    tA = tB; tB = tC;
  }
}

extern "C" void kernel_launch(void* const* d_in, const int* in_sizes, int n_in,
                              void* d_out, int out_size, void* d_ws, size_t ws_size,
                              hipStream_t stream) {
  (void)in_sizes; (void)n_in; (void)out_size; (void)ws_size;
  const float* q = (const float*)d_in[0];
  const float* b = (const float*)d_in[1];
  const float* P = (const float*)d_in[2];
  const float* H = (const float*)d_in[3];
  float* ws = (float*)d_ws;
  float* Xs = (float*)d_out;
  float* out2 = Xs + (size_t)BATCH * (ITERS + 1) * 128;

  setup_kernel<<<2, 64, 0, stream>>>(P, H, ws);
  iter_kernel<<<BATCH, 64, 0, stream>>>(q, b, ws, Xs);
  primal_kernel<<<BATCH, 512, 0, stream>>>(b, ws, Xs, out2);
}